// Round 1
// baseline (299.464 us; speedup 1.0000x reference)
//
#include <hip/hip_runtime.h>
#include <math.h>

#define Gn 64
#define Nn 1000
#define En 8192
#define Cc 128
#define HIDn 256
#define NHn 4
#define DHn 32
#define EPSf 1e-5f

// ---------------- degree count ----------------
__global__ __launch_bounds__(256) void k_count(const int* __restrict__ ei, int* __restrict__ deg)
{
    int g = blockIdx.y;
    const int* dstp = ei + (size_t)g * 2 * En + En;
    for (int e = blockIdx.x * blockDim.x + threadIdx.x; e < En; e += gridDim.x * blockDim.x) {
        atomicAdd(&deg[g * Nn + dstp[e]], 1);
    }
}

// ---------------- per-graph exclusive scan + dinv ----------------
__global__ __launch_bounds__(1024) void k_scan(const int* __restrict__ deg, int* __restrict__ offs,
                                               int* __restrict__ cursor, float* __restrict__ dinv)
{
    __shared__ int sb[1024];
    int g = blockIdx.x, t = threadIdx.x;
    int d = (t < Nn) ? deg[g * Nn + t] : 0;
    sb[t] = d;
    __syncthreads();
    for (int st = 1; st < 1024; st <<= 1) {
        int v = (t >= st) ? sb[t - st] : 0;
        __syncthreads();
        sb[t] += v;
        __syncthreads();
    }
    if (t < Nn) {
        int ex = sb[t] - d;  // exclusive prefix
        offs[g * Nn + t] = ex;
        cursor[g * Nn + t] = ex;
        dinv[g * Nn + t] = rsqrtf((float)d + 1.0f);
    }
}

// ---------------- CSR fill (counting sort by dst) ----------------
__global__ __launch_bounds__(256) void k_fill(const int* __restrict__ ei, int* __restrict__ cursor,
                                              int* __restrict__ csr)
{
    int g = blockIdx.y;
    const int* srcp = ei + (size_t)g * 2 * En;
    const int* dstp = srcp + En;
    for (int e = blockIdx.x * blockDim.x + threadIdx.x; e < En; e += gridDim.x * blockDim.x) {
        int dd = dstp[e];
        int p = atomicAdd(&cursor[g * Nn + dd], 1);
        csr[(size_t)g * En + p] = srcp[e];
    }
}

// ---------------- fp32 GEMM: H[g] = X[g] @ W  (N x 128 @ 128 x 128) ----------------
__global__ __launch_bounds__(256) void k_gemm(const float* __restrict__ X, const float* __restrict__ W,
                                              float* __restrict__ Hout)
{
    __shared__ float Xs[64][128];
    int g = blockIdx.y;
    int r0 = blockIdx.x * 64;
    const float* Xg = X + (size_t)g * Nn * Cc;
    float* Hg = Hout + (size_t)g * Nn * Cc;
    int t = threadIdx.x;

    // stage 64x128 X tile (zero-pad rows >= Nn)
    #pragma unroll
    for (int i = 0; i < 8; ++i) {
        int id = t + i * 256;          // float4 id in [0,2048)
        int rr = id >> 5;              // row in tile
        int kk = (id & 31) * 4;        // col
        float4 v = make_float4(0.f, 0.f, 0.f, 0.f);
        if (r0 + rr < Nn) v = *(const float4*)(Xg + (size_t)(r0 + rr) * Cc + kk);
        *(float4*)(&Xs[rr][kk]) = v;
    }
    __syncthreads();

    int tx = t & 31, ty = t >> 5;      // tx: col quad, ty: row group
    int c = tx * 4;
    float4 acc[8];
    #pragma unroll
    for (int r = 0; r < 8; ++r) acc[r] = make_float4(0.f, 0.f, 0.f, 0.f);

    #pragma unroll 4
    for (int k = 0; k < 128; ++k) {
        float4 wv = *(const float4*)(W + k * Cc + c);
        #pragma unroll
        for (int r = 0; r < 8; ++r) {
            float a = Xs[ty + r * 8][k];
            acc[r].x += a * wv.x; acc[r].y += a * wv.y;
            acc[r].z += a * wv.z; acc[r].w += a * wv.w;
        }
    }

    #pragma unroll
    for (int r = 0; r < 8; ++r) {
        int rr = r0 + ty + r * 8;
        if (rr < Nn) *(float4*)(Hg + (size_t)rr * Cc + c) = acc[r];
    }
}

// ---------------- combine: out = tanh(b + dinv^2*H[n] + sum_in dinv[s]dinv[n]*H[s]) ----------------
// if hout == nullptr: accumulate tanh result into pooled[g][c] instead of storing.
__global__ __launch_bounds__(256) void k_combine(const float* __restrict__ Hin, const int* __restrict__ csr,
                                                 const int* __restrict__ offs, const int* __restrict__ deg,
                                                 const float* __restrict__ dinv, const float* __restrict__ bias,
                                                 float* __restrict__ hout, float* __restrict__ pooled)
{
    int g = blockIdx.y;
    const float* Hg = Hin + (size_t)g * Nn * Cc;
    const int* csrg = csr + (size_t)g * En;
    int wave = threadIdx.x >> 6, lane = threadIdx.x & 63;
    int c = lane * 2;
    const float2 bb = *(const float2*)(bias + c);
    float2 pacc = make_float2(0.f, 0.f);

    for (int n = blockIdx.x * 4 + wave; n < Nn; n += gridDim.x * 4) {
        float dv = dinv[g * Nn + n];
        int st = offs[g * Nn + n];
        int dc = deg[g * Nn + n];
        float2 hv = *(const float2*)(Hg + (size_t)n * Cc + c);
        float2 acc;
        acc.x = hv.x * dv * dv + bb.x;
        acc.y = hv.y * dv * dv + bb.y;
        for (int e = 0; e < dc; ++e) {
            int s = csrg[st + e];
            float w = dinv[g * Nn + s] * dv;
            float2 hs = *(const float2*)(Hg + (size_t)s * Cc + c);
            acc.x += hs.x * w;
            acc.y += hs.y * w;
        }
        float tx = tanhf(acc.x), ty2 = tanhf(acc.y);
        if (hout) {
            float2 th = make_float2(tx, ty2);
            *(float2*)(hout + (size_t)g * Nn * Cc + (size_t)n * Cc + c) = th;
        } else {
            pacc.x += tx; pacc.y += ty2;
        }
    }
    if (!hout) {
        atomicAdd(&pooled[g * Cc + c], pacc.x);
        atomicAdd(&pooled[g * Cc + c + 1], pacc.y);
    }
}

// ---------------- qkv = pooled @ in_w.T + in_b  (64 x 384) ----------------
__global__ __launch_bounds__(256) void k_qkv(const float* __restrict__ pooled, const float* __restrict__ in_w,
                                             const float* __restrict__ in_b, float* __restrict__ qkv)
{
    int idx = blockIdx.x * 256 + threadIdx.x;   // 96 blocks * 256 = 24576 = 64*384
    int i = idx / 384, j = idx % 384;
    const float* gp = pooled + i * Cc;
    const float* wr = in_w + j * Cc;
    float acc = in_b[j];
    #pragma unroll 4
    for (int k = 0; k < Cc; ++k) acc += gp[k] * wr[k];
    qkv[idx] = acc;
}

// ---------------- per-head attention ----------------
__global__ __launch_bounds__(256) void k_attn(const float* __restrict__ qkv, float* __restrict__ ob)
{
    __shared__ float qs[64][DHn], ks[64][DHn], vs[64][DHn], S[64][64];
    int h = blockIdx.x, t = threadIdx.x;

    for (int idx = t; idx < 64 * DHn; idx += 256) {
        int i = idx >> 5, d = idx & 31;
        qs[i][d] = qkv[i * 384 + h * DHn + d];
        ks[i][d] = qkv[i * 384 + Cc + h * DHn + d];
        vs[i][d] = qkv[i * 384 + 2 * Cc + h * DHn + d];
    }
    __syncthreads();

    const float scale = 0.17677669529663687f;   // 1/sqrt(32)
    for (int idx = t; idx < 64 * 64; idx += 256) {
        int i = idx >> 6, j = idx & 63;
        float a = 0.f;
        #pragma unroll
        for (int d = 0; d < DHn; ++d) a += qs[i][d] * ks[j][d];
        S[i][j] = a * scale;
    }
    __syncthreads();

    int lane = t & 63, wv = t >> 6;
    for (int r = wv; r < 64; r += 4) {
        float v = S[r][lane];
        float m = v;
        #pragma unroll
        for (int o = 32; o > 0; o >>= 1) m = fmaxf(m, __shfl_xor(m, o));
        float e = expf(v - m);
        float s = e;
        #pragma unroll
        for (int o = 32; o > 0; o >>= 1) s += __shfl_xor(s, o);
        S[r][lane] = e / s;
    }
    __syncthreads();

    for (int idx = t; idx < 64 * DHn; idx += 256) {
        int i = idx >> 5, d = idx & 31;
        float a = 0.f;
        for (int k = 0; k < 64; ++k) a += S[i][k] * vs[k][d];
        ob[i * Cc + h * DHn + d] = a;
    }
}

// ---------------- per-row: out-proj + MLP + LN + relu-accumulate ----------------
__global__ __launch_bounds__(256) void k_row(const float* __restrict__ ob, const float* __restrict__ out_w,
                                             const float* __restrict__ out_b, const float* __restrict__ mw1,
                                             const float* __restrict__ mb1, const float* __restrict__ mw2,
                                             const float* __restrict__ mb2, const float* __restrict__ ln2g,
                                             const float* __restrict__ ln2b, float* __restrict__ repr)
{
    __shared__ float orow[Cc], xatt[Cc], m1[HIDn], ybuf[Cc], red[Cc];
    int i = blockIdx.x, t = threadIdx.x;

    if (t < Cc) orow[t] = ob[i * Cc + t];
    __syncthreads();

    if (t < Cc) {
        float acc = out_b[t];
        #pragma unroll 4
        for (int k = 0; k < Cc; ++k) acc += orow[k] * out_w[t * Cc + k];
        xatt[t] = acc;
    }
    __syncthreads();

    {   // all 256 threads: m1[t]
        float acc = mb1[t];
        #pragma unroll 4
        for (int k = 0; k < Cc; ++k) acc += xatt[k] * mw1[k * HIDn + t];
        m1[t] = fmaxf(acc, 0.f);
    }
    __syncthreads();

    if (t < Cc) {
        float acc = mb2[t];
        #pragma unroll 4
        for (int j = 0; j < HIDn; ++j) acc += m1[j] * mw2[j * Cc + t];
        ybuf[t] = xatt[t] + acc;
    }
    __syncthreads();

    // layernorm over 128
    if (t < Cc) red[t] = ybuf[t];
    __syncthreads();
    for (int s2 = 64; s2 > 0; s2 >>= 1) {
        if (t < s2) red[t] += red[t + s2];
        __syncthreads();
    }
    float mu = red[0] * (1.f / Cc);
    __syncthreads();
    if (t < Cc) { float d = ybuf[t] - mu; red[t] = d * d; }
    __syncthreads();
    for (int s2 = 64; s2 > 0; s2 >>= 1) {
        if (t < s2) red[t] += red[t + s2];
        __syncthreads();
    }
    float var = red[0] * (1.f / Cc);
    float rstd = rsqrtf(var + EPSf);
    if (t < Cc) {
        float z = (ybuf[t] - mu) * rstd * ln2g[t] + ln2b[t];
        float r = fmaxf(z, 0.f);
        atomicAdd(&repr[t], r);
    }
}

// ---------------- final: logits = repr @ lw + lb ----------------
__global__ __launch_bounds__(128) void k_final(const float* __restrict__ repr, const float* __restrict__ lw,
                                               const float* __restrict__ lb, float* __restrict__ out)
{
    __shared__ float r0[Cc], r1[Cc];
    int t = threadIdx.x;
    float r = repr[t];
    r0[t] = r * lw[t * 2 + 0];
    r1[t] = r * lw[t * 2 + 1];
    __syncthreads();
    for (int s2 = 64; s2 > 0; s2 >>= 1) {
        if (t < s2) { r0[t] += r0[t + s2]; r1[t] += r1[t + s2]; }
        __syncthreads();
    }
    if (t == 0) {
        out[0] = r0[0] + lb[0];
        out[1] = r1[0] + lb[1];
    }
}

extern "C" void kernel_launch(void* const* d_in, const int* in_sizes, int n_in,
                              void* d_out, int out_size, void* d_ws, size_t ws_size,
                              hipStream_t stream)
{
    const float* x     = (const float*)d_in[0];
    const int*   ei    = (const int*)d_in[1];
    const float* W0    = (const float*)d_in[2];
    const float* b0    = (const float*)d_in[3];
    const float* W1    = (const float*)d_in[4];
    const float* b1    = (const float*)d_in[5];
    const float* in_w  = (const float*)d_in[6];
    const float* in_b  = (const float*)d_in[7];
    const float* out_w = (const float*)d_in[8];
    const float* out_b = (const float*)d_in[9];
    const float* ln2g  = (const float*)d_in[10];
    const float* ln2b  = (const float*)d_in[11];
    const float* mw1   = (const float*)d_in[12];
    const float* mb1   = (const float*)d_in[13];
    const float* mw2   = (const float*)d_in[14];
    const float* mb2   = (const float*)d_in[15];
    const float* lw    = (const float*)d_in[16];
    const float* lb    = (const float*)d_in[17];
    float* out = (float*)d_out;

    char* ws = (char*)d_ws;
    size_t off = 0;
    auto carve = [&](size_t bytes) { size_t o = off; off += (bytes + 255) & ~(size_t)255; return o; };
    size_t o_deg  = carve((size_t)Gn * Nn * 4);
    size_t o_pool = carve((size_t)Gn * Cc * 4);
    size_t o_repr = carve((size_t)Cc * 4);
    size_t zbytes = off;                       // [deg | pooled | repr] zeroed each launch
    size_t o_dinv = carve((size_t)Gn * Nn * 4);
    size_t o_offs = carve((size_t)Gn * Nn * 4);
    size_t o_cur  = carve((size_t)Gn * Nn * 4);
    size_t o_csr  = carve((size_t)Gn * En * 4);
    size_t o_qkv  = carve((size_t)Gn * 384 * 4);
    size_t o_ob   = carve((size_t)Gn * Cc * 4);
    size_t o_bufA = carve((size_t)Gn * Nn * Cc * 4);
    size_t o_bufB = carve((size_t)Gn * Nn * Cc * 4);
    (void)ws_size; (void)in_sizes; (void)n_in; (void)out_size;

    int*   deg    = (int*)(ws + o_deg);
    float* pooled = (float*)(ws + o_pool);
    float* repr   = (float*)(ws + o_repr);
    float* dinv   = (float*)(ws + o_dinv);
    int*   offs   = (int*)(ws + o_offs);
    int*   cur    = (int*)(ws + o_cur);
    int*   csr    = (int*)(ws + o_csr);
    float* qkvb   = (float*)(ws + o_qkv);
    float* ob     = (float*)(ws + o_ob);
    float* bufA   = (float*)(ws + o_bufA);
    float* bufB   = (float*)(ws + o_bufB);

    hipMemsetAsync(d_ws, 0, zbytes, stream);
    k_count<<<dim3(4, Gn), 256, 0, stream>>>(ei, deg);
    k_scan<<<Gn, 1024, 0, stream>>>(deg, offs, cur, dinv);
    k_fill<<<dim3(4, Gn), 256, 0, stream>>>(ei, cur, csr);

    k_gemm<<<dim3(16, Gn), 256, 0, stream>>>(x, W0, bufA);
    k_combine<<<dim3(32, Gn), 256, 0, stream>>>(bufA, csr, offs, deg, dinv, b0, bufB, nullptr);
    k_gemm<<<dim3(16, Gn), 256, 0, stream>>>(bufB, W1, bufA);
    k_combine<<<dim3(32, Gn), 256, 0, stream>>>(bufA, csr, offs, deg, dinv, b1, nullptr, pooled);

    k_qkv<<<96, 256, 0, stream>>>(pooled, in_w, in_b, qkvb);
    k_attn<<<NHn, 256, 0, stream>>>(qkvb, ob);
    k_row<<<Gn, 256, 0, stream>>>(ob, out_w, out_b, mw1, mb1, mw2, mb2, ln2g, ln2b, repr);
    k_final<<<1, 128, 0, stream>>>(repr, lw, lb, out);
}